// Round 1
// baseline (250.416 us; speedup 1.0000x reference)
//
#include <hip/hip_runtime.h>
#include <math.h>

#define SPAT  96
#define IMG   (SPAT*SPAT)        /* 9216    */
#define PLANE (SPAT*SPAT*SPAT)   /* 884736  */
#define ROWCH (IMG/4)            /* float4 chunks per (cc,d) tile: 96h * 24 = 2304 */

// ---------------------------------------------------------------------------
// 4x4 matrix inverse (adjugate)
// ---------------------------------------------------------------------------
__device__ inline void invert4(const float m[16], float inv[16]) {
    inv[0]  =  m[5]*m[10]*m[15] - m[5]*m[11]*m[14] - m[9]*m[6]*m[15] + m[9]*m[7]*m[14] + m[13]*m[6]*m[11] - m[13]*m[7]*m[10];
    inv[4]  = -m[4]*m[10]*m[15] + m[4]*m[11]*m[14] + m[8]*m[6]*m[15] - m[8]*m[7]*m[14] - m[12]*m[6]*m[11] + m[12]*m[7]*m[10];
    inv[8]  =  m[4]*m[9]*m[15]  - m[4]*m[11]*m[13] - m[8]*m[5]*m[15] + m[8]*m[7]*m[13] + m[12]*m[5]*m[11] - m[12]*m[7]*m[9];
    inv[12] = -m[4]*m[9]*m[14]  + m[4]*m[10]*m[13] + m[8]*m[5]*m[14] - m[8]*m[6]*m[13] - m[12]*m[5]*m[10] + m[12]*m[6]*m[9];
    inv[1]  = -m[1]*m[10]*m[15] + m[1]*m[11]*m[14] + m[9]*m[2]*m[15] - m[9]*m[3]*m[14] - m[13]*m[2]*m[11] + m[13]*m[3]*m[10];
    inv[5]  =  m[0]*m[10]*m[15] - m[0]*m[11]*m[14] - m[8]*m[2]*m[15] + m[8]*m[3]*m[14] + m[12]*m[2]*m[11] - m[12]*m[3]*m[10];
    inv[9]  = -m[0]*m[9]*m[15]  + m[0]*m[11]*m[13] + m[8]*m[1]*m[15] - m[8]*m[3]*m[13] - m[12]*m[1]*m[11] + m[12]*m[3]*m[9];
    inv[13] =  m[0]*m[9]*m[14]  - m[0]*m[10]*m[13] - m[8]*m[1]*m[14] + m[8]*m[2]*m[13] + m[12]*m[1]*m[10] - m[12]*m[2]*m[9];
    inv[2]  =  m[1]*m[6]*m[15]  - m[1]*m[7]*m[14]  - m[5]*m[2]*m[15] + m[5]*m[3]*m[14] + m[13]*m[2]*m[7]  - m[13]*m[3]*m[6];
    inv[6]  = -m[0]*m[6]*m[15]  + m[0]*m[7]*m[14]  + m[4]*m[2]*m[15] - m[4]*m[3]*m[14] - m[12]*m[2]*m[7]  + m[12]*m[3]*m[6];
    inv[10] =  m[0]*m[5]*m[15]  - m[0]*m[7]*m[13]  - m[4]*m[1]*m[15] + m[4]*m[3]*m[13] + m[12]*m[1]*m[7]  - m[12]*m[3]*m[5];
    inv[14] = -m[0]*m[5]*m[14]  + m[0]*m[6]*m[13]  + m[4]*m[1]*m[14] - m[4]*m[2]*m[13] - m[12]*m[1]*m[6]  + m[12]*m[2]*m[5];
    inv[3]  = -m[1]*m[6]*m[11]  + m[1]*m[7]*m[10]  + m[5]*m[2]*m[11] - m[5]*m[3]*m[10] - m[9]*m[2]*m[7]   + m[9]*m[3]*m[6];
    inv[7]  =  m[0]*m[6]*m[11]  - m[0]*m[7]*m[10]  - m[4]*m[2]*m[11] + m[4]*m[3]*m[10] + m[8]*m[2]*m[7]   - m[8]*m[3]*m[6];
    inv[11] = -m[0]*m[5]*m[11]  + m[0]*m[7]*m[9]   + m[4]*m[1]*m[11] - m[4]*m[3]*m[9]  - m[8]*m[1]*m[7]   + m[8]*m[3]*m[5];
    inv[15] =  m[0]*m[5]*m[10]  - m[0]*m[6]*m[9]   - m[4]*m[1]*m[10] + m[4]*m[2]*m[9]  + m[8]*m[1]*m[6]   - m[8]*m[2]*m[5];
    float det  = m[0]*inv[0] + m[1]*inv[4] + m[2]*inv[8] + m[3]*inv[12];
    float rdet = 1.0f / det;
    for (int i = 0; i < 16; ++i) inv[i] *= rdet;
}

// ---------------------------------------------------------------------------
// Fused single-pass kernel: every output float4 chunk is written EXACTLY once.
// blockIdx.x = d (0..95), blockIdx.y = cc (0..63, = b*32 + c).
// Per block: sb / folded affine Ms / d-terms are uniform (one LDS broadcast,
// then SGPR-resident). Hot loop per chunk (9 iters x 256 thr = 2304 chunks):
//   h = tl/24 (magic mul), bx = fma, interval test (fma+min/max+2 cmp),
//   coalesced float4 store. Rare path (~1 chunk per 24-chunk h-row) does
//   the trilinear taps from the 2.4 MB L2-resident image.
// ---------------------------------------------------------------------------
__global__ __launch_bounds__(256) void fused_kernel(
        const float* __restrict__ xin,   // [2,32,96,96]
        const float* __restrict__ aff_in,// [2,2,4,4]
        float4* __restrict__ out) {      // [2,32,96,96,96] as float4 chunks
    __shared__ float Ms[12];
    const int d  = blockIdx.x;           // 0..95
    const int cc = blockIdx.y;           // 0..63 = b*32 + c
    const int b  = cc >> 5;
    const int s  = (cc >> 4) & 1;
    const int sb = s * 2 + b;

    if (threadIdx.x == 0) {
        float A[16];
        #pragma unroll
        for (int i = 0; i < 16; ++i) A[i] = aff_in[sb * 16 + i];
        #pragma unroll
        for (int j = 0; j < 3; ++j) {    // column-normalize by zooms
            float z = sqrtf(A[0*4+j]*A[0*4+j] + A[1*4+j]*A[1*4+j] + A[2*4+j]*A[2*4+j]);
            float rz = 1.0f / z;
            #pragma unroll
            for (int i = 0; i < 4; ++i) A[i*4+j] *= rz;
        }
        float inv[16];
        invert4(A, inv);
        #pragma unroll
        for (int r = 0; r < 3; ++r) {
            float T0 = inv[r*4+0], T1 = inv[r*4+1], T2 = inv[r*4+2], T3 = inv[r*4+3];
            // i_r = T0*w + T1*h + T2*d + [-47.5*(T0+T1+T2) + 48*T3 + 47.5]
            Ms[r*4+0] = T0;
            Ms[r*4+1] = T1;
            Ms[r*4+2] = T2;
            Ms[r*4+3] = -47.5f * (T0 + T1 + T2) + 48.0f * T3 + 47.5f;
        }
    }
    __syncthreads();

    const float Mxw = Ms[0], Mxh = Ms[1], Mxd = Ms[2],  Mx0 = Ms[3];
    const float Myw = Ms[4], Myh = Ms[5], Myd = Ms[6],  My0 = Ms[7];
    const float Mzw = Ms[8], Mzh = Ms[9], Mzd = Ms[10], Mz0 = Ms[11];

    const float fd   = (float)d;
    const float bx_d = Mxd * fd + Mx0;
    const float by_d = Myd * fd + My0;
    const float bz_d = Mzd * fd + Mz0;

    const float* img = xin + (size_t)cc * IMG;
    float4* op = out + ((size_t)cc * (PLANE / 4) + (size_t)d * (IMG / 4));

    #pragma unroll 3
    for (int it = 0; it < 9; ++it) {
        int tl = (int)threadIdx.x + 256 * it;   // 0..2303
        int h  = tl / 24;                        // magic-mul division
        int w4 = tl - h * 24;
        float fh  = (float)h;
        float bx  = Mxh * fh + bx_d;
        float fw0 = (float)(w4 << 2);
        float ix0 = Mxw * fw0 + bx;
        float ix3 = ix0 + 3.0f * Mxw;

        float4 v = make_float4(0.f, 0.f, 0.f, 0.f);
        // chunk contributes iff the continuous ix-span overlaps (47,49)
        if (fmaxf(ix0, ix3) > 47.0f && fminf(ix0, ix3) < 49.0f) {
            float by = Myh * fh + by_d;
            float bz = Mzh * fh + bz_d;
            float vv[4];
            #pragma unroll
            for (int j = 0; j < 4; ++j) {
                float fw = fw0 + (float)j;
                float ix = Mxw * fw + bx;
                float wx = 1.0f - fabsf(ix - 48.0f);
                float r = 0.0f;
                if (wx > 0.0f) {
                    float iy = Myw * fw + by;
                    float iz = Mzw * fw + bz;
                    float yf = floorf(iy), zf = floorf(iz);
                    float fy = iy - yf,    fz = iz - zf;
                    int y0 = (int)yf, z0 = (int)zf;
                    bool vy0 = (y0 >= 0)  & (y0 <  SPAT);
                    bool vy1 = (y0 >= -1) & (y0 <  SPAT - 1);
                    bool vz0 = (z0 >= 0)  & (z0 <  SPAT);
                    bool vz1 = (z0 >= -1) & (z0 <  SPAT - 1);
                    int y0c = min(max(y0, 0),     SPAT - 1);
                    int y1c = min(max(y0 + 1, 0), SPAT - 1);
                    int z0c = min(max(z0, 0),     SPAT - 1);
                    int z1c = min(max(z0 + 1, 0), SPAT - 1);
                    float wy0 = 1.0f - fy, wy1 = fy;
                    float wz0 = 1.0f - fz, wz1 = fz;
                    float w00 = wx * wz0 * wy0 * ((vz0 & vy0) ? 1.0f : 0.0f);
                    float w01 = wx * wz0 * wy1 * ((vz0 & vy1) ? 1.0f : 0.0f);
                    float w10 = wx * wz1 * wy0 * ((vz1 & vy0) ? 1.0f : 0.0f);
                    float w11 = wx * wz1 * wy1 * ((vz1 & vy1) ? 1.0f : 0.0f);
                    r = w00 * img[z0c * SPAT + y0c] + w01 * img[z0c * SPAT + y1c]
                      + w10 * img[z1c * SPAT + y0c] + w11 * img[z1c * SPAT + y1c];
                }
                vv[j] = r;
            }
            v = make_float4(vv[0], vv[1], vv[2], vv[3]);
        }
        op[tl] = v;   // coalesced: 64 lanes x 16 B contiguous
    }
}

extern "C" void kernel_launch(void* const* d_in, const int* in_sizes, int n_in,
                              void* d_out, int out_size, void* d_ws, size_t ws_size,
                              hipStream_t stream) {
    const float* x   = (const float*)d_in[0];   // [2,32,96,96] fp32
    const float* aff = (const float*)d_in[1];   // [2,2,4,4]    fp32
    float* out = (float*)d_out;                 // [2,32,96,96,96] fp32

    // single pass: each output chunk written exactly once (zero or sampled)
    dim3 grid(SPAT, 64);                        // (d, b*32+c)
    fused_kernel<<<grid, 256, 0, stream>>>(x, aff, (float4*)out);
}

// Round 2
// 223.179 us; speedup vs baseline: 1.1220x; 1.1220x over previous
//
#include <hip/hip_runtime.h>
#include <math.h>

#define SPAT  96
#define IMG   (SPAT*SPAT)        /* 9216    */
#define PLANE (SPAT*SPAT*SPAT)   /* 884736  */

// ---------------------------------------------------------------------------
// 4x4 matrix inverse (adjugate)
// ---------------------------------------------------------------------------
__device__ inline void invert4(const float m[16], float inv[16]) {
    inv[0]  =  m[5]*m[10]*m[15] - m[5]*m[11]*m[14] - m[9]*m[6]*m[15] + m[9]*m[7]*m[14] + m[13]*m[6]*m[11] - m[13]*m[7]*m[10];
    inv[4]  = -m[4]*m[10]*m[15] + m[4]*m[11]*m[14] + m[8]*m[6]*m[15] - m[8]*m[7]*m[14] - m[12]*m[6]*m[11] + m[12]*m[7]*m[10];
    inv[8]  =  m[4]*m[9]*m[15]  - m[4]*m[11]*m[13] - m[8]*m[5]*m[15] + m[8]*m[7]*m[13] + m[12]*m[5]*m[11] - m[12]*m[7]*m[9];
    inv[12] = -m[4]*m[9]*m[14]  + m[4]*m[10]*m[13] + m[8]*m[5]*m[14] - m[8]*m[6]*m[13] - m[12]*m[5]*m[10] + m[12]*m[6]*m[9];
    inv[1]  = -m[1]*m[10]*m[15] + m[1]*m[11]*m[14] + m[9]*m[2]*m[15] - m[9]*m[3]*m[14] - m[13]*m[2]*m[11] + m[13]*m[3]*m[10];
    inv[5]  =  m[0]*m[10]*m[15] - m[0]*m[11]*m[14] - m[8]*m[2]*m[15] + m[8]*m[3]*m[14] + m[12]*m[2]*m[11] - m[12]*m[3]*m[10];
    inv[9]  = -m[0]*m[9]*m[15]  + m[0]*m[11]*m[13] + m[8]*m[1]*m[15] - m[8]*m[3]*m[13] - m[12]*m[1]*m[11] + m[12]*m[3]*m[9];
    inv[13] =  m[0]*m[9]*m[14]  - m[0]*m[10]*m[13] - m[8]*m[1]*m[14] + m[8]*m[2]*m[13] + m[12]*m[1]*m[10] - m[12]*m[2]*m[9];
    inv[2]  =  m[1]*m[6]*m[15]  - m[1]*m[7]*m[14]  - m[5]*m[2]*m[15] + m[5]*m[3]*m[14] + m[13]*m[2]*m[7]  - m[13]*m[3]*m[6];
    inv[6]  = -m[0]*m[6]*m[15]  + m[0]*m[7]*m[14]  + m[4]*m[2]*m[15] - m[4]*m[3]*m[14] - m[12]*m[2]*m[7]  + m[12]*m[3]*m[6];
    inv[10] =  m[0]*m[5]*m[15]  - m[0]*m[7]*m[13]  - m[4]*m[1]*m[15] + m[4]*m[3]*m[13] + m[12]*m[1]*m[7]  - m[12]*m[3]*m[5];
    inv[14] = -m[0]*m[5]*m[14]  + m[0]*m[6]*m[13]  + m[4]*m[1]*m[14] - m[4]*m[2]*m[13] - m[12]*m[1]*m[6]  + m[12]*m[2]*m[5];
    inv[3]  = -m[1]*m[6]*m[11]  + m[1]*m[7]*m[10]  + m[5]*m[2]*m[11] - m[5]*m[3]*m[10] - m[9]*m[2]*m[7]   + m[9]*m[3]*m[6];
    inv[7]  =  m[0]*m[6]*m[11]  - m[0]*m[7]*m[10]  - m[4]*m[2]*m[11] + m[4]*m[3]*m[10] + m[8]*m[2]*m[7]   - m[8]*m[3]*m[6];
    inv[11] = -m[0]*m[5]*m[11]  + m[0]*m[7]*m[9]   + m[4]*m[1]*m[11] - m[4]*m[3]*m[9]  - m[8]*m[1]*m[7]   + m[8]*m[3]*m[5];
    inv[15] =  m[0]*m[5]*m[10]  - m[0]*m[6]*m[9]   - m[4]*m[1]*m[10] + m[4]*m[2]*m[9]  + m[8]*m[1]*m[6]   - m[8]*m[2]*m[5];
    float det  = m[0]*inv[0] + m[1]*inv[4] + m[2]*inv[8] + m[3]*inv[12];
    float rdet = 1.0f / det;
    for (int i = 0; i < 16; ++i) inv[i] *= rdet;
}

// ---------------------------------------------------------------------------
// Single-pass, two-phase kernel. blockIdx = (d, cc).
// Phase 1: branch-free stream-zero of the whole 36 KB (cc,d) tile
//          (9 unconditional float4 stores/thread — fill-kernel instr mix).
// __syncthreads(): vmcnt(0) drain before s_barrier => phase-1 stores are
//          globally complete => WAW with phase 2 is ordered.
// Phase 2: threads 0..95 own h-row = tid; closed-form w-interval per row;
//          only the ~6% contributing chunks run the trilinear body.
// ---------------------------------------------------------------------------
__global__ __launch_bounds__(256) void fused2_kernel(
        const float* __restrict__ xin,   // [2,32,96,96]
        const float* __restrict__ aff_in,// [2,2,4,4]
        float4* __restrict__ out) {      // [2,32,96,96,96] as float4 chunks
    __shared__ float Ms[12];
    const int d  = blockIdx.x;           // 0..95
    const int cc = blockIdx.y;           // 0..63 = b*32 + c
    const int b  = cc >> 5;
    const int s  = (cc >> 4) & 1;
    const int sb = s * 2 + b;

    if (threadIdx.x == 0) {
        float A[16];
        #pragma unroll
        for (int i = 0; i < 16; ++i) A[i] = aff_in[sb * 16 + i];
        #pragma unroll
        for (int j = 0; j < 3; ++j) {    // column-normalize by zooms
            float z = sqrtf(A[0*4+j]*A[0*4+j] + A[1*4+j]*A[1*4+j] + A[2*4+j]*A[2*4+j]);
            float rz = 1.0f / z;
            #pragma unroll
            for (int i = 0; i < 4; ++i) A[i*4+j] *= rz;
        }
        float inv[16];
        invert4(A, inv);
        #pragma unroll
        for (int r = 0; r < 3; ++r) {
            float T0 = inv[r*4+0], T1 = inv[r*4+1], T2 = inv[r*4+2], T3 = inv[r*4+3];
            // i_r = T0*w + T1*h + T2*d + [-47.5*(T0+T1+T2) + 48*T3 + 47.5]
            Ms[r*4+0] = T0;
            Ms[r*4+1] = T1;
            Ms[r*4+2] = T2;
            Ms[r*4+3] = -47.5f * (T0 + T1 + T2) + 48.0f * T3 + 47.5f;
        }
    }

    // ---- phase 1: stream-zero the tile (no Ms dependence, no branches) ----
    float4* op = out + ((size_t)cc * (PLANE / 4) + (size_t)d * (IMG / 4));
    const float4 z4 = make_float4(0.f, 0.f, 0.f, 0.f);
    #pragma unroll
    for (int it = 0; it < 9; ++it)
        op[(int)threadIdx.x + 256 * it] = z4;

    __syncthreads();   // Ms visible + phase-1 stores drained (vmcnt(0) before barrier)

    // ---- phase 2: sparse slab overwrite, one h-row per thread (tid<96) ----
    const int h = (int)threadIdx.x;
    if (h >= SPAT) return;

    const float Mxw = Ms[0], Mxh = Ms[1], Mxd = Ms[2],  Mx0 = Ms[3];
    const float Myw = Ms[4], Myh = Ms[5], Myd = Ms[6],  My0 = Ms[7];
    const float Mzw = Ms[8], Mzh = Ms[9], Mzd = Ms[10], Mz0 = Ms[11];

    const float fh = (float)h, fd = (float)d;
    const float bx = Mxh * fh + Mxd * fd + Mx0;

    // contributing w interval: |Mxw*w + bx - 48| < 1
    int wlo, whi;
    if (fabsf(Mxw) > 1e-6f) {
        float rMxw = 1.0f / Mxw;
        float w1 = (47.0f - bx) * rMxw;
        float w2 = (49.0f - bx) * rMxw;
        float wmin = fminf(w1, w2), wmax = fmaxf(w1, w2);
        wlo = max((int)ceilf(wmin), 0);
        whi = min((int)floorf(wmax), SPAT - 1);
    } else {
        bool in = fabsf(bx - 48.0f) < 1.0f;
        wlo = in ? 0 : 1;
        whi = in ? SPAT - 1 : 0;
    }
    if (wlo > whi) return;

    const float by = Myh * fh + Myd * fd + My0;
    const float bz = Mzh * fh + Mzd * fd + Mz0;
    const float* img = xin + (size_t)cc * IMG;

    const int qlo = wlo >> 2, qhi = whi >> 2;
    for (int q = qlo; q <= qhi; ++q) {
        float vv[4];
        #pragma unroll
        for (int j = 0; j < 4; ++j) {
            float fw = (float)(4 * q + j);
            float ix = Mxw * fw + bx;
            float wx = 1.0f - fabsf(ix - 48.0f);
            float r = 0.0f;
            if (wx > 0.0f) {
                float iy = Myw * fw + by;
                float iz = Mzw * fw + bz;
                float yf = floorf(iy), zf = floorf(iz);
                float fy = iy - yf,    fz = iz - zf;
                int y0 = (int)yf, z0 = (int)zf;
                bool vy0 = (y0 >= 0)  & (y0 <  SPAT);
                bool vy1 = (y0 >= -1) & (y0 <  SPAT - 1);
                bool vz0 = (z0 >= 0)  & (z0 <  SPAT);
                bool vz1 = (z0 >= -1) & (z0 <  SPAT - 1);
                int y0c = min(max(y0, 0),     SPAT - 1);
                int y1c = min(max(y0 + 1, 0), SPAT - 1);
                int z0c = min(max(z0, 0),     SPAT - 1);
                int z1c = min(max(z0 + 1, 0), SPAT - 1);
                float wy0 = 1.0f - fy, wy1 = fy;
                float wz0 = 1.0f - fz, wz1 = fz;
                float w00 = wx * wz0 * wy0 * ((vz0 & vy0) ? 1.0f : 0.0f);
                float w01 = wx * wz0 * wy1 * ((vz0 & vy1) ? 1.0f : 0.0f);
                float w10 = wx * wz1 * wy0 * ((vz1 & vy0) ? 1.0f : 0.0f);
                float w11 = wx * wz1 * wy1 * ((vz1 & vy1) ? 1.0f : 0.0f);
                r = w00 * img[z0c * SPAT + y0c] + w01 * img[z0c * SPAT + y1c]
                  + w10 * img[z1c * SPAT + y0c] + w11 * img[z1c * SPAT + y1c];
            }
            vv[j] = r;
        }
        op[h * 24 + q] = make_float4(vv[0], vv[1], vv[2], vv[3]);
    }
}

extern "C" void kernel_launch(void* const* d_in, const int* in_sizes, int n_in,
                              void* d_out, int out_size, void* d_ws, size_t ws_size,
                              hipStream_t stream) {
    const float* x   = (const float*)d_in[0];   // [2,32,96,96] fp32
    const float* aff = (const float*)d_in[1];   // [2,2,4,4]    fp32
    float* out = (float*)d_out;                 // [2,32,96,96,96] fp32

    dim3 grid(SPAT, 64);                        // (d, b*32+c); one pass total
    fused2_kernel<<<grid, 256, 0, stream>>>(x, aff, (float4*)out);
}